// Round 2
// baseline (1266.452 us; speedup 1.0000x reference)
//
#include <hip/hip_runtime.h>

#define H 256
#define FANOUT 10

// ---------------------------------------------------------------------------
// agg[t][:] = 0.1 * sum_{k<10} src[row[t*10+k]][:]
// One block (64 threads, float4 lanes) per target row.
// ---------------------------------------------------------------------------
__global__ __launch_bounds__(64) void agg_kernel(
    const float* __restrict__ src, const int* __restrict__ row,
    float* __restrict__ agg, int n_tgt) {
  int t = blockIdx.x;
  if (t >= n_tgt) return;
  int tid = threadIdx.x;  // 0..63
  const int base = t * FANOUT;
  float4 acc = {0.f, 0.f, 0.f, 0.f};
#pragma unroll
  for (int k = 0; k < FANOUT; ++k) {
    int r = row[base + k];
    const float4 v =
        *reinterpret_cast<const float4*>(src + (size_t)r * H + tid * 4);
    acc.x += v.x; acc.y += v.y; acc.z += v.z; acc.w += v.w;
  }
  acc.x *= 0.1f; acc.y *= 0.1f; acc.z *= 0.1f; acc.w *= 0.1f;
  *reinterpret_cast<float4*>(agg + (size_t)t * H + tid * 4) = acc;
}

// ---------------------------------------------------------------------------
// out = agg @ Wl^T + bl + xt @ Wr^T  (+ optional relu)
// f32 vector GEMM: 64x64 tile per block, 16x16 threads, 4x4 per thread,
// two K=256 passes (agg/Wl then xt/Wr).
// ---------------------------------------------------------------------------
#define BM 64
#define BN 64
#define BK 16
#define LDP 68  // padded LDS stride (17 float4s -> 16B-aligned rows)

__global__ __launch_bounds__(256) void sage_gemm(
    const float* __restrict__ agg, const float* __restrict__ xt,
    const float* __restrict__ Wl, const float* __restrict__ bl,
    const float* __restrict__ Wr, float* __restrict__ out,
    int n_tgt, int do_relu) {
  __shared__ float As[BK * LDP];
  __shared__ float Bs[BK * LDP];
  const int tid = threadIdx.x;
  const int tx = tid & 15;        // col group
  const int ty = tid >> 4;        // row group
  const int row0 = blockIdx.x * BM;
  const int col0 = blockIdx.y * BN;

  float acc[4][4] = {};

  const int lr = tid >> 2;         // 0..63 tile row (or W row)
  const int lc = (tid & 3) * 4;    // 0,4,8,12 k offset

  for (int pass = 0; pass < 2; ++pass) {
    const float* __restrict__ A = pass ? xt : agg;
    const float* __restrict__ W = pass ? Wr : Wl;
    for (int kt = 0; kt < H; kt += BK) {
      // A tile -> As[k][m]
      float4 va = {0.f, 0.f, 0.f, 0.f};
      if (row0 + lr < n_tgt)
        va = *reinterpret_cast<const float4*>(A + (size_t)(row0 + lr) * H + kt + lc);
      // B tile -> Bs[k][n]   (W is (256,256), col0+lr < 256 always)
      const float4 vb =
          *reinterpret_cast<const float4*>(W + (size_t)(col0 + lr) * H + kt + lc);
      __syncthreads();
      As[(lc + 0) * LDP + lr] = va.x;
      As[(lc + 1) * LDP + lr] = va.y;
      As[(lc + 2) * LDP + lr] = va.z;
      As[(lc + 3) * LDP + lr] = va.w;
      Bs[(lc + 0) * LDP + lr] = vb.x;
      Bs[(lc + 1) * LDP + lr] = vb.y;
      Bs[(lc + 2) * LDP + lr] = vb.z;
      Bs[(lc + 3) * LDP + lr] = vb.w;
      __syncthreads();
#pragma unroll
      for (int kk = 0; kk < BK; ++kk) {
        float a[4], b[4];
#pragma unroll
        for (int i = 0; i < 4; ++i) a[i] = As[kk * LDP + ty * 4 + i];
#pragma unroll
        for (int j = 0; j < 4; ++j) b[j] = Bs[kk * LDP + tx * 4 + j];
#pragma unroll
        for (int i = 0; i < 4; ++i)
#pragma unroll
          for (int j = 0; j < 4; ++j) acc[i][j] += a[i] * b[j];
      }
    }
  }

  // epilogue: + bias, relu, store (float4 per row)
  const int cbase = col0 + tx * 4;
  float4 bias = *reinterpret_cast<const float4*>(bl + cbase);
#pragma unroll
  for (int i = 0; i < 4; ++i) {
    int r = row0 + ty * 4 + i;
    if (r >= n_tgt) continue;
    float4 v;
    v.x = acc[i][0] + bias.x;
    v.y = acc[i][1] + bias.y;
    v.z = acc[i][2] + bias.z;
    v.w = acc[i][3] + bias.w;
    if (do_relu) {
      v.x = fmaxf(v.x, 0.f); v.y = fmaxf(v.y, 0.f);
      v.z = fmaxf(v.z, 0.f); v.w = fmaxf(v.w, 0.f);
    }
    *reinterpret_cast<float4*>(out + (size_t)r * H + cbase) = v;
  }
}

// ---------------------------------------------------------------------------
// exclusive prefix sum of counts (B=4096) -> off[0..B], single block
// ---------------------------------------------------------------------------
__global__ __launch_bounds__(1024) void scan_kernel(
    const int* __restrict__ cnt, int* __restrict__ off, int B) {
  __shared__ int sdata[1024];
  const int t = threadIdx.x;
  const int base = t * 4;
  int c[4];
#pragma unroll
  for (int k = 0; k < 4; ++k) c[k] = (base + k < B) ? cnt[base + k] : 0;
  int s0 = c[0];
  int s1 = s0 + c[1];
  int s2 = s1 + c[2];
  int s3 = s2 + c[3];
  sdata[t] = s3;
  __syncthreads();
  for (int o = 1; o < 1024; o <<= 1) {
    int v = (t >= o) ? sdata[t - o] : 0;
    __syncthreads();
    sdata[t] += v;
    __syncthreads();
  }
  int excl = sdata[t] - s3;
  if (base + 0 < B) off[base + 0] = excl;
  if (base + 1 < B) off[base + 1] = excl + s0;
  if (base + 2 < B) off[base + 2] = excl + s1;
  if (base + 3 < B) off[base + 3] = excl + s2;
  if (t == 1023) off[B] = sdata[1023];
}

// ---------------------------------------------------------------------------
// pooled[b] = mean over users of user_out[inv_idx[off[b]..off[b]+cnt[b])]
// ---------------------------------------------------------------------------
__global__ __launch_bounds__(64) void pool_kernel(
    const float* __restrict__ uo, const int* __restrict__ idx,
    const int* __restrict__ off, const int* __restrict__ cnt,
    float* __restrict__ pooled) {
  const int b = blockIdx.x;
  const int tid = threadIdx.x;  // 0..63
  const int o = off[b];
  const int n = cnt[b];
  float4 acc = {0.f, 0.f, 0.f, 0.f};
  for (int k = 0; k < n; ++k) {
    int u = idx[o + k];
    const float4 v =
        *reinterpret_cast<const float4*>(uo + (size_t)u * H + tid * 4);
    acc.x += v.x; acc.y += v.y; acc.z += v.z; acc.w += v.w;
  }
  const float inv = 1.0f / (float)n;
  acc.x *= inv; acc.y *= inv; acc.z *= inv; acc.w *= inv;
  *reinterpret_cast<float4*>(pooled + (size_t)b * H + tid * 4) = acc;
}

// ---------------------------------------------------------------------------
// out[b] = [res_out[b], pooled[b]] @ W_out^T + b_out   (W_out: (2,512))
// ---------------------------------------------------------------------------
__global__ __launch_bounds__(256) void out_kernel(
    const float* __restrict__ res_out, const float* __restrict__ pooled,
    const float* __restrict__ Wout, const float* __restrict__ bout,
    float* __restrict__ out) {
  const int b = blockIdx.x;
  const int t = threadIdx.x;  // 0..255
  const float e0 = res_out[(size_t)b * H + t];
  const float e1 = pooled[(size_t)b * H + t];
  float p0 = e0 * Wout[t] + e1 * Wout[256 + t];
  float p1 = e0 * Wout[512 + t] + e1 * Wout[768 + t];
#pragma unroll
  for (int o = 32; o >= 1; o >>= 1) {
    p0 += __shfl_down(p0, o, 64);
    p1 += __shfl_down(p1, o, 64);
  }
  __shared__ float s0[4], s1[4];
  const int w = t >> 6, lane = t & 63;
  if (lane == 0) { s0[w] = p0; s1[w] = p1; }
  __syncthreads();
  if (t == 0) out[(size_t)b * 2 + 0] = s0[0] + s0[1] + s0[2] + s0[3] + bout[0];
  if (t == 1) out[(size_t)b * 2 + 1] = s1[0] + s1[1] + s1[2] + s1[3] + bout[1];
}

// ---------------------------------------------------------------------------
extern "C" void kernel_launch(void* const* d_in, const int* in_sizes, int n_in,
                              void* d_out, int out_size, void* d_ws,
                              size_t ws_size, hipStream_t stream) {
  const float* res_x  = (const float*)d_in[0];
  const float* user_x = (const float*)d_in[1];
  const int* res_ei[3]  = {(const int*)d_in[2], (const int*)d_in[3], (const int*)d_in[4]};
  const int* user_ei[3] = {(const int*)d_in[5], (const int*)d_in[6], (const int*)d_in[7]};

  // robust to num_users_per_res / inverse_idx ordering
  const int* counts;
  const int* inv_idx;
  if (in_sizes[8] == 4096) { counts = (const int*)d_in[8]; inv_idx = (const int*)d_in[9]; }
  else                     { counts = (const int*)d_in[9]; inv_idx = (const int*)d_in[8]; }

  const float* rW[9]; const float* uW[9];
  for (int i = 0; i < 9; ++i) rW[i] = (const float*)d_in[10 + i];
  for (int i = 0; i < 9; ++i) uW[i] = (const float*)d_in[19 + i];
  const float* Wout = (const float*)d_in[28];
  const float* bout = (const float*)d_in[29];

  // workspace layout (floats)
  float* ws = (float*)d_ws;
  float* A    = ws;                       // agg scratch: 60000*256
  float* B1   = A    + (size_t)60000 * H; // u1 then r1
  float* B2   = B1   + (size_t)60000 * H; // u2 then r2
  float* U3   = B2   + (size_t)20000 * H; // user_out 8192*256
  float* R3   = U3   + (size_t)8192  * H; // res_out 4096*256
  float* POOL = R3   + (size_t)4096  * H;
  int*   OFF  = (int*)(POOL + (size_t)4096 * H);

  auto run_layer = [&](const float* src, const int* ei_row, int n_tgt,
                       const float* Wl, const float* bl, const float* Wr,
                       float* outbuf, int relu) {
    agg_kernel<<<n_tgt, 64, 0, stream>>>(src, ei_row, A, n_tgt);
    dim3 g((n_tgt + BM - 1) / BM, H / BN);
    sage_gemm<<<g, 256, 0, stream>>>(A, src, Wl, bl, Wr, outbuf, n_tgt, relu);
  };

  // user branch: 250000 -> 60000 -> 20000 -> 8192
  run_layer(user_x, user_ei[0], 60000, uW[0], uW[1], uW[2], B1, 1);
  run_layer(B1,     user_ei[1], 20000, uW[3], uW[4], uW[5], B2, 0);
  run_layer(B2,     user_ei[2], 8192,  uW[6], uW[7], uW[8], U3, 1);

  // res branch: 200000 -> 50000 -> 12000 -> 4096
  run_layer(res_x,  res_ei[0],  50000, rW[0], rW[1], rW[2], B1, 1);
  run_layer(B1,     res_ei[1],  12000, rW[3], rW[4], rW[5], B2, 0);
  run_layer(B2,     res_ei[2],  4096,  rW[6], rW[7], rW[8], R3, 1);

  // pooling + final linear
  scan_kernel<<<1, 1024, 0, stream>>>(counts, OFF, 4096);
  pool_kernel<<<4096, 64, 0, stream>>>(U3, inv_idx, OFF, counts, POOL);
  out_kernel<<<4096, 256, 0, stream>>>(R3, POOL, Wout, bout, (float*)d_out);
}

// Round 3
// 1164.195 us; speedup vs baseline: 1.0878x; 1.0878x over previous
//
#include <hip/hip_runtime.h>

#define H 256
#define FANOUT 10

typedef __attribute__((ext_vector_type(8))) short bf16x8;
typedef __attribute__((ext_vector_type(4))) float f32x4;

__device__ __forceinline__ unsigned short f2bf(float x) {
  unsigned int u = __float_as_uint(x);
  u += 0x7FFFu + ((u >> 16) & 1u);
  return (unsigned short)(u >> 16);
}
__device__ __forceinline__ float bf2f(unsigned short h) {
  return __uint_as_float(((unsigned int)h) << 16);
}

// ---------------------------------------------------------------------------
// Weight prep: 12 (256,256) f32 matrices -> bf16 hi plane + lo plane each.
// WB layout: [mat][hi 65536 | lo 65536] ushorts.
// ---------------------------------------------------------------------------
struct PtrPack { const float* p[12]; };

__global__ __launch_bounds__(256) void wprep_kernel(PtrPack pk,
                                                    unsigned short* __restrict__ WB) {
  int g = blockIdx.x * 256 + threadIdx.x;  // 12*65536 total
  int mat = g >> 16;
  int e = g & 65535;
  float x = pk.p[mat][e];
  unsigned short h = f2bf(x);
  float r = x - bf2f(h);
  WB[(size_t)mat * 131072 + e] = h;
  WB[(size_t)mat * 131072 + 65536 + e] = f2bf(r);
}

// ---------------------------------------------------------------------------
// agg (f32 source, layer 0): mean of 10 gathered rows -> bf16 hi/lo planes
// ---------------------------------------------------------------------------
__global__ __launch_bounds__(64) void agg_f32(
    const float* __restrict__ src, const int* __restrict__ row,
    unsigned short* __restrict__ ahi, unsigned short* __restrict__ alo, int n_tgt) {
  int t = blockIdx.x;
  if (t >= n_tgt) return;
  int tid = threadIdx.x;
  const int base = t * FANOUT;
  float4 acc = {0.f, 0.f, 0.f, 0.f};
#pragma unroll
  for (int k = 0; k < FANOUT; ++k) {
    int r = row[base + k];
    const float4 v = *reinterpret_cast<const float4*>(src + (size_t)r * H + tid * 4);
    acc.x += v.x; acc.y += v.y; acc.z += v.z; acc.w += v.w;
  }
  acc.x *= 0.1f; acc.y *= 0.1f; acc.z *= 0.1f; acc.w *= 0.1f;
  ushort4 h, l;
  h.x = f2bf(acc.x); l.x = f2bf(acc.x - bf2f(h.x));
  h.y = f2bf(acc.y); l.y = f2bf(acc.y - bf2f(h.y));
  h.z = f2bf(acc.z); l.z = f2bf(acc.z - bf2f(h.z));
  h.w = f2bf(acc.w); l.w = f2bf(acc.w - bf2f(h.w));
  *reinterpret_cast<ushort4*>(ahi + (size_t)t * H + tid * 4) = h;
  *reinterpret_cast<ushort4*>(alo + (size_t)t * H + tid * 4) = l;
}

// ---------------------------------------------------------------------------
// agg (bf16 hi/lo source, layers 1,2)
// ---------------------------------------------------------------------------
__global__ __launch_bounds__(64) void agg_bf(
    const unsigned short* __restrict__ shi, const unsigned short* __restrict__ slo,
    const int* __restrict__ row,
    unsigned short* __restrict__ ahi, unsigned short* __restrict__ alo, int n_tgt) {
  int t = blockIdx.x;
  if (t >= n_tgt) return;
  int tid = threadIdx.x;
  const int base = t * FANOUT;
  float4 acc = {0.f, 0.f, 0.f, 0.f};
#pragma unroll
  for (int k = 0; k < FANOUT; ++k) {
    int r = row[base + k];
    size_t p = (size_t)r * H + tid * 4;
    const ushort4 vh = *reinterpret_cast<const ushort4*>(shi + p);
    const ushort4 vl = *reinterpret_cast<const ushort4*>(slo + p);
    acc.x += bf2f(vh.x) + bf2f(vl.x);
    acc.y += bf2f(vh.y) + bf2f(vl.y);
    acc.z += bf2f(vh.z) + bf2f(vl.z);
    acc.w += bf2f(vh.w) + bf2f(vl.w);
  }
  acc.x *= 0.1f; acc.y *= 0.1f; acc.z *= 0.1f; acc.w *= 0.1f;
  ushort4 h, l;
  h.x = f2bf(acc.x); l.x = f2bf(acc.x - bf2f(h.x));
  h.y = f2bf(acc.y); l.y = f2bf(acc.y - bf2f(h.y));
  h.z = f2bf(acc.z); l.z = f2bf(acc.z - bf2f(h.z));
  h.w = f2bf(acc.w); l.w = f2bf(acc.w - bf2f(h.w));
  *reinterpret_cast<ushort4*>(ahi + (size_t)t * H + tid * 4) = h;
  *reinterpret_cast<ushort4*>(alo + (size_t)t * H + tid * 4) = l;
}

// ---------------------------------------------------------------------------
// MFMA GEMM: out = agg @ Wl^T + bl + xt @ Wr^T   (split-bf16, 3 MFMA/frag)
// Block: 512 thr = 8 waves (2 row x 4 col), tile 128x256, BK=32.
// A staged in LDS (double-buffered); B (weights) read from L2 as fragments.
// XT32: pass-1 A source is f32 (layer-0 xt), else bf16 hi/lo planes.
// ---------------------------------------------------------------------------
template <int XT32>
__global__ __launch_bounds__(512, 1) void sage_gemm_mfma(
    const unsigned short* __restrict__ Ahi, const unsigned short* __restrict__ Alo,
    const unsigned short* __restrict__ Xhi, const unsigned short* __restrict__ Xlo,
    const float* __restrict__ Xf,
    const unsigned short* __restrict__ Wl2, const unsigned short* __restrict__ Wr2,
    const float* __restrict__ bias,
    unsigned short* __restrict__ Ohi, unsigned short* __restrict__ Olo,
    int n_tgt, int relu) {
  __shared__ unsigned short lds[2][2][128 * 32];  // [buf][hi/lo] 32 KB
  const int tid = threadIdx.x;
  const int lane = tid & 63, wid = tid >> 6;
  const int wr = wid >> 2, wc = wid & 3;
  const int l15 = lane & 15, lk = lane >> 4;
  const int m0 = blockIdx.x * 128;
  const int srow = tid >> 2, sch = tid & 3;
  const int grow = m0 + srow;
  const bool sok = grow < n_tgt;

  f32x4 acc[4][4];
#pragma unroll
  for (int i = 0; i < 4; ++i)
#pragma unroll
    for (int j = 0; j < 4; ++j) acc[i][j] = (f32x4){0.f, 0.f, 0.f, 0.f};

  auto stage = [&](int buf, int s) {
    const int pass = s >> 3;
    const int kt = (s & 7) * 32;
    const int goff = grow * H + kt + sch * 8;
    bf16x8 vh = {0, 0, 0, 0, 0, 0, 0, 0};
    bf16x8 vl = {0, 0, 0, 0, 0, 0, 0, 0};
    if (sok) {
      if (pass == 0) {
        vh = *reinterpret_cast<const bf16x8*>(Ahi + goff);
        vl = *reinterpret_cast<const bf16x8*>(Alo + goff);
      } else if (XT32) {
        const float4 f0 = *reinterpret_cast<const float4*>(Xf + goff);
        const float4 f1 = *reinterpret_cast<const float4*>(Xf + goff + 4);
        const float xs[8] = {f0.x, f0.y, f0.z, f0.w, f1.x, f1.y, f1.z, f1.w};
#pragma unroll
        for (int i = 0; i < 8; ++i) {
          unsigned short h = f2bf(xs[i]);
          vh[i] = (short)h;
          vl[i] = (short)f2bf(xs[i] - bf2f(h));
        }
      } else {
        vh = *reinterpret_cast<const bf16x8*>(Xhi + goff);
        vl = *reinterpret_cast<const bf16x8*>(Xlo + goff);
      }
    }
    *reinterpret_cast<bf16x8*>(&lds[buf][0][srow * 32 + sch * 8]) = vh;
    *reinterpret_cast<bf16x8*>(&lds[buf][1][srow * 32 + sch * 8]) = vl;
  };

  stage(0, 0);
  __syncthreads();

  for (int s = 0; s < 16; ++s) {
    const int buf = s & 1;
    if (s < 15) stage(buf ^ 1, s + 1);
    const int pass = s >> 3;
    const int kt = (s & 7) * 32;
    const unsigned short* __restrict__ W = pass ? Wr2 : Wl2;
    bf16x8 bh[4], bl[4];
#pragma unroll
    for (int nf = 0; nf < 4; ++nf) {
      const int n = wc * 64 + nf * 16 + l15;
      const int off = n * H + kt + lk * 8;
      bh[nf] = *reinterpret_cast<const bf16x8*>(W + off);
      bl[nf] = *reinterpret_cast<const bf16x8*>(W + 65536 + off);
    }
    bf16x8 ah[4], al[4];
#pragma unroll
    for (int mf = 0; mf < 4; ++mf) {
      const int soff = (wr * 64 + mf * 16 + l15) * 32 + lk * 8;
      ah[mf] = *reinterpret_cast<const bf16x8*>(&lds[buf][0][soff]);
      al[mf] = *reinterpret_cast<const bf16x8*>(&lds[buf][1][soff]);
    }
#pragma unroll
    for (int mf = 0; mf < 4; ++mf)
#pragma unroll
      for (int nf = 0; nf < 4; ++nf) {
        acc[mf][nf] = __builtin_amdgcn_mfma_f32_16x16x32_bf16(ah[mf], bh[nf], acc[mf][nf], 0, 0, 0);
        acc[mf][nf] = __builtin_amdgcn_mfma_f32_16x16x32_bf16(ah[mf], bl[nf], acc[mf][nf], 0, 0, 0);
        acc[mf][nf] = __builtin_amdgcn_mfma_f32_16x16x32_bf16(al[mf], bh[nf], acc[mf][nf], 0, 0, 0);
      }
    __syncthreads();
  }

  // epilogue: +bias, relu, split f32 -> bf16 hi/lo planes
#pragma unroll
  for (int nf = 0; nf < 4; ++nf) {
    const int c = wc * 64 + nf * 16 + l15;
    const float bv = bias[c];
#pragma unroll
    for (int mf = 0; mf < 4; ++mf) {
      const int r0 = m0 + wr * 64 + mf * 16 + lk * 4;
#pragma unroll
      for (int j = 0; j < 4; ++j) {
        const int r = r0 + j;
        if (r < n_tgt) {
          float v = acc[mf][nf][j] + bv;
          if (relu) v = fmaxf(v, 0.f);
          unsigned short h = f2bf(v);
          Ohi[(size_t)r * H + c] = h;
          Olo[(size_t)r * H + c] = f2bf(v - bf2f(h));
        }
      }
    }
  }
}

// ---------------------------------------------------------------------------
// exclusive prefix sum of counts (B=4096) -> off[0..B], single block
// ---------------------------------------------------------------------------
__global__ __launch_bounds__(1024) void scan_kernel(
    const int* __restrict__ cnt, int* __restrict__ off, int B) {
  __shared__ int sdata[1024];
  const int t = threadIdx.x;
  const int base = t * 4;
  int c[4];
#pragma unroll
  for (int k = 0; k < 4; ++k) c[k] = (base + k < B) ? cnt[base + k] : 0;
  int s0 = c[0];
  int s1 = s0 + c[1];
  int s2 = s1 + c[2];
  int s3 = s2 + c[3];
  sdata[t] = s3;
  __syncthreads();
  for (int o = 1; o < 1024; o <<= 1) {
    int v = (t >= o) ? sdata[t - o] : 0;
    __syncthreads();
    sdata[t] += v;
    __syncthreads();
  }
  int excl = sdata[t] - s3;
  if (base + 0 < B) off[base + 0] = excl;
  if (base + 1 < B) off[base + 1] = excl + s0;
  if (base + 2 < B) off[base + 2] = excl + s1;
  if (base + 3 < B) off[base + 3] = excl + s2;
  if (t == 1023) off[B] = sdata[1023];
}

// ---------------------------------------------------------------------------
// pooled[b] = mean over users of U3 planes -> f32
// ---------------------------------------------------------------------------
__global__ __launch_bounds__(64) void pool_kernel(
    const unsigned short* __restrict__ uhi, const unsigned short* __restrict__ ulo,
    const int* __restrict__ idx, const int* __restrict__ off,
    const int* __restrict__ cnt, float* __restrict__ pooled) {
  const int b = blockIdx.x;
  const int tid = threadIdx.x;
  const int o = off[b];
  const int n = cnt[b];
  float4 acc = {0.f, 0.f, 0.f, 0.f};
  for (int k = 0; k < n; ++k) {
    int u = idx[o + k];
    size_t p = (size_t)u * H + tid * 4;
    const ushort4 vh = *reinterpret_cast<const ushort4*>(uhi + p);
    const ushort4 vl = *reinterpret_cast<const ushort4*>(ulo + p);
    acc.x += bf2f(vh.x) + bf2f(vl.x);
    acc.y += bf2f(vh.y) + bf2f(vl.y);
    acc.z += bf2f(vh.z) + bf2f(vl.z);
    acc.w += bf2f(vh.w) + bf2f(vl.w);
  }
  const float inv = 1.0f / (float)n;
  acc.x *= inv; acc.y *= inv; acc.z *= inv; acc.w *= inv;
  *reinterpret_cast<float4*>(pooled + (size_t)b * H + tid * 4) = acc;
}

// ---------------------------------------------------------------------------
// out[b] = [res_out[b], pooled[b]] @ W_out^T + b_out   (W_out: (2,512))
// ---------------------------------------------------------------------------
__global__ __launch_bounds__(256) void out_kernel(
    const unsigned short* __restrict__ rhi, const unsigned short* __restrict__ rlo,
    const float* __restrict__ pooled,
    const float* __restrict__ Wout, const float* __restrict__ bout,
    float* __restrict__ out) {
  const int b = blockIdx.x;
  const int t = threadIdx.x;  // 0..255
  const float e0 = bf2f(rhi[(size_t)b * H + t]) + bf2f(rlo[(size_t)b * H + t]);
  const float e1 = pooled[(size_t)b * H + t];
  float p0 = e0 * Wout[t] + e1 * Wout[256 + t];
  float p1 = e0 * Wout[512 + t] + e1 * Wout[768 + t];
#pragma unroll
  for (int o = 32; o >= 1; o >>= 1) {
    p0 += __shfl_down(p0, o, 64);
    p1 += __shfl_down(p1, o, 64);
  }
  __shared__ float s0[4], s1[4];
  const int w = t >> 6, lane = t & 63;
  if (lane == 0) { s0[w] = p0; s1[w] = p1; }
  __syncthreads();
  if (t == 0) out[(size_t)b * 2 + 0] = s0[0] + s0[1] + s0[2] + s0[3] + bout[0];
  if (t == 1) out[(size_t)b * 2 + 1] = s1[0] + s1[1] + s1[2] + s1[3] + bout[1];
}

// ---------------------------------------------------------------------------
extern "C" void kernel_launch(void* const* d_in, const int* in_sizes, int n_in,
                              void* d_out, int out_size, void* d_ws,
                              size_t ws_size, hipStream_t stream) {
  const float* res_x  = (const float*)d_in[0];
  const float* user_x = (const float*)d_in[1];
  const int* res_ei[3]  = {(const int*)d_in[2], (const int*)d_in[3], (const int*)d_in[4]};
  const int* user_ei[3] = {(const int*)d_in[5], (const int*)d_in[6], (const int*)d_in[7]};

  const int* counts;
  const int* inv_idx;
  if (in_sizes[8] == 4096) { counts = (const int*)d_in[8]; inv_idx = (const int*)d_in[9]; }
  else                     { counts = (const int*)d_in[9]; inv_idx = (const int*)d_in[8]; }

  const float* rW[9]; const float* uW[9];
  for (int i = 0; i < 9; ++i) rW[i] = (const float*)d_in[10 + i];
  for (int i = 0; i < 9; ++i) uW[i] = (const float*)d_in[19 + i];
  const float* Wout = (const float*)d_in[28];
  const float* bout = (const float*)d_in[29];

  // workspace layout (ushorts)
  unsigned short* u = (unsigned short*)d_ws;
  const size_t P0 = (size_t)60000 * H;   // max agg/layer1 rows
  const size_t P2 = (size_t)20000 * H;
  const size_t P3 = (size_t)8192 * H;
  const size_t P4 = (size_t)4096 * H;
  unsigned short* AGGh = u;
  unsigned short* AGGl = u + P0;
  unsigned short* B1h  = u + 2 * P0;
  unsigned short* B1l  = u + 3 * P0;
  unsigned short* B2h  = u + 4 * P0;
  unsigned short* B2l  = u + 4 * P0 + P2;
  unsigned short* U3h  = u + 4 * P0 + 2 * P2;
  unsigned short* U3l  = u + 4 * P0 + 2 * P2 + P3;
  unsigned short* R3h  = u + 4 * P0 + 2 * P2 + 2 * P3;
  unsigned short* R3l  = u + 4 * P0 + 2 * P2 + 2 * P3 + P4;
  unsigned short* WB   = u + 4 * P0 + 2 * P2 + 2 * P3 + 2 * P4;
  int* OFF             = (int*)(WB + (size_t)12 * 131072);
  float* POOL          = (float*)B2h;  // dead after res L2 gemm

  // weight prep: order uWl0,uWr0,uWl1,uWr1,uWl2,uWr2,rWl0,rWr0,...
  PtrPack pk;
  pk.p[0] = uW[0]; pk.p[1] = uW[2];
  pk.p[2] = uW[3]; pk.p[3] = uW[5];
  pk.p[4] = uW[6]; pk.p[5] = uW[8];
  pk.p[6] = rW[0]; pk.p[7] = rW[2];
  pk.p[8] = rW[3]; pk.p[9] = rW[5];
  pk.p[10] = rW[6]; pk.p[11] = rW[8];
  wprep_kernel<<<3072, 256, 0, stream>>>(pk, WB);

  auto Wm = [&](int m) { return WB + (size_t)m * 131072; };
  auto grid = [](int n) { return (n + 127) / 128; };

  // ---- user branch: 250000 -> 60000 -> 20000 -> 8192
  agg_f32<<<60000, 64, 0, stream>>>(user_x, user_ei[0], AGGh, AGGl, 60000);
  sage_gemm_mfma<1><<<grid(60000), 512, 0, stream>>>(
      AGGh, AGGl, nullptr, nullptr, user_x, Wm(0), Wm(1), uW[1], B1h, B1l, 60000, 1);
  agg_bf<<<20000, 64, 0, stream>>>(B1h, B1l, user_ei[1], AGGh, AGGl, 20000);
  sage_gemm_mfma<0><<<grid(20000), 512, 0, stream>>>(
      AGGh, AGGl, B1h, B1l, nullptr, Wm(2), Wm(3), uW[4], B2h, B2l, 20000, 0);
  agg_bf<<<8192, 64, 0, stream>>>(B2h, B2l, user_ei[2], AGGh, AGGl, 8192);
  sage_gemm_mfma<0><<<grid(8192), 512, 0, stream>>>(
      AGGh, AGGl, B2h, B2l, nullptr, Wm(4), Wm(5), uW[7], U3h, U3l, 8192, 1);

  // ---- res branch: 200000 -> 50000 -> 12000 -> 4096
  agg_f32<<<50000, 64, 0, stream>>>(res_x, res_ei[0], AGGh, AGGl, 50000);
  sage_gemm_mfma<1><<<grid(50000), 512, 0, stream>>>(
      AGGh, AGGl, nullptr, nullptr, res_x, Wm(6), Wm(7), rW[1], B1h, B1l, 50000, 1);
  agg_bf<<<12000, 64, 0, stream>>>(B1h, B1l, res_ei[1], AGGh, AGGl, 12000);
  sage_gemm_mfma<0><<<grid(12000), 512, 0, stream>>>(
      AGGh, AGGl, B1h, B1l, nullptr, Wm(8), Wm(9), rW[4], B2h, B2l, 12000, 0);
  agg_bf<<<4096, 64, 0, stream>>>(B2h, B2l, res_ei[2], AGGh, AGGl, 4096);
  sage_gemm_mfma<0><<<grid(4096), 512, 0, stream>>>(
      AGGh, AGGl, B2h, B2l, nullptr, Wm(10), Wm(11), rW[7], R3h, R3l, 4096, 1);

  // ---- pooling + final linear
  scan_kernel<<<1, 1024, 0, stream>>>(counts, OFF, 4096);
  pool_kernel<<<4096, 64, 0, stream>>>(U3h, U3l, inv_idx, OFF, counts, POOL);
  out_kernel<<<4096, 256, 0, stream>>>(R3h, R3l, POOL, Wout, bout, (float*)d_out);
}

// Round 4
// 1067.633 us; speedup vs baseline: 1.1862x; 1.0904x over previous
//
#include <hip/hip_runtime.h>

#define H 256
#define FANOUT 10

typedef __attribute__((ext_vector_type(8))) short bf16x8;
typedef __attribute__((ext_vector_type(4))) float f32x4;

__device__ __forceinline__ unsigned short f2bf(float x) {
  unsigned int u = __float_as_uint(x);
  u += 0x7FFFu + ((u >> 16) & 1u);
  return (unsigned short)(u >> 16);
}
__device__ __forceinline__ float bf2f(unsigned short h) {
  return __uint_as_float(((unsigned int)h) << 16);
}

// ---------------------------------------------------------------------------
// Weight prep: 12 (256,256) f32 matrices -> bf16 hi plane + lo plane each.
// WB layout: [mat][hi 65536 | lo 65536] ushorts.
// ---------------------------------------------------------------------------
struct PtrPack { const float* p[12]; };

__global__ __launch_bounds__(256) void wprep_kernel(PtrPack pk,
                                                    unsigned short* __restrict__ WB) {
  int g = blockIdx.x * 256 + threadIdx.x;  // 12*65536 total
  int mat = g >> 16;
  int e = g & 65535;
  float x = pk.p[mat][e];
  unsigned short h = f2bf(x);
  float r = x - bf2f(h);
  WB[(size_t)mat * 131072 + e] = h;
  WB[(size_t)mat * 131072 + 65536 + e] = f2bf(r);
}

// ---------------------------------------------------------------------------
// agg[t][:] = 0.1 * sum_{k<10} src[row[t*10+k]][:]   (f32 in, f32 out)
// 256-thread blocks, 4 targets per block (one wave each) -> 32 waves/CU max.
// ---------------------------------------------------------------------------
__global__ __launch_bounds__(256) void agg_kernel(
    const float* __restrict__ src, const int* __restrict__ row,
    float* __restrict__ agg, int n_tgt) {
  const int t = blockIdx.x * 4 + (threadIdx.x >> 6);
  if (t >= n_tgt) return;
  const int lane = threadIdx.x & 63;
  const int base = t * FANOUT;
  float4 acc = {0.f, 0.f, 0.f, 0.f};
#pragma unroll
  for (int k = 0; k < FANOUT; ++k) {
    int r = row[base + k];
    const float4 v =
        *reinterpret_cast<const float4*>(src + (size_t)r * H + lane * 4);
    acc.x += v.x; acc.y += v.y; acc.z += v.z; acc.w += v.w;
  }
  acc.x *= 0.1f; acc.y *= 0.1f; acc.z *= 0.1f; acc.w *= 0.1f;
  *reinterpret_cast<float4*>(agg + (size_t)t * H + lane * 4) = acc;
}

// ---------------------------------------------------------------------------
// MFMA GEMM: Out = Af @ Wl^T + bias + Xf @ Wr^T  (+relu), all features f32.
// Split-bf16 (hi+lo) emulation: 3 MFMA per fragment pair.
// Tile 64x256, 256 thr = 4 waves (1 row x 4 col), BK=32, 16 K-steps.
// A staged f32->bf16hi/lo into LDS in MFMA-fragment-native layout:
//   lds[buf][plane][subtile(4)][lane(64)][8]  -> ds_read/write_b128 linear,
//   zero bank conflicts. B (weights, pre-split) read from L2 per step.
// ---------------------------------------------------------------------------
__global__ __launch_bounds__(256, 2) void sage_gemm_mfma(
    const float* __restrict__ Af, const float* __restrict__ Xf,
    const unsigned short* __restrict__ Wl2, const unsigned short* __restrict__ Wr2,
    const float* __restrict__ bias, float* __restrict__ Out,
    int n_tgt, int relu) {
  __shared__ unsigned short lds[2][2][4 * 64 * 8];  // 16 KB
  const int tid = threadIdx.x;
  const int lane = tid & 63, wc = tid >> 6;
  const int l15 = lane & 15, lk = lane >> 4;
  const int m0 = blockIdx.x * 64;
  const int srow = tid >> 2, sch = tid & 3;   // staging: row 0..63, k-chunk 0..3
  const int grow = m0 + srow;
  const bool sok = grow < n_tgt;
  // fragment-native LDS slot for this thread's staged 8 elems:
  const int ldsoff = (((srow >> 4) * 64) + (srow & 15) + sch * 16) * 8;

  f32x4 acc[4][4];
#pragma unroll
  for (int i = 0; i < 4; ++i)
#pragma unroll
    for (int j = 0; j < 4; ++j) acc[i][j] = (f32x4){0.f, 0.f, 0.f, 0.f};

  float4 f0 = {0, 0, 0, 0}, f1 = {0, 0, 0, 0};
  auto gload = [&](int s) {
    if (sok) {
      const float* S = (s >> 3) ? Xf : Af;
      const float* p = S + (size_t)grow * H + (s & 7) * 32 + sch * 8;
      f0 = *reinterpret_cast<const float4*>(p);
      f1 = *reinterpret_cast<const float4*>(p + 4);
    } else {
      f0 = (float4){0, 0, 0, 0};
      f1 = (float4){0, 0, 0, 0};
    }
  };
  auto sconv = [&](int buf) {
    const float xs[8] = {f0.x, f0.y, f0.z, f0.w, f1.x, f1.y, f1.z, f1.w};
    bf16x8 vh, vl;
#pragma unroll
    for (int i = 0; i < 8; ++i) {
      unsigned short h = f2bf(xs[i]);
      vh[i] = (short)h;
      vl[i] = (short)f2bf(xs[i] - bf2f(h));
    }
    *reinterpret_cast<bf16x8*>(&lds[buf][0][ldsoff]) = vh;
    *reinterpret_cast<bf16x8*>(&lds[buf][1][ldsoff]) = vl;
  };

  gload(0);
  sconv(0);
  __syncthreads();

  for (int s = 0; s < 16; ++s) {
    const int buf = s & 1;
    if (s < 15) gload(s + 1);  // issue early; converts after MFMA (T14 split)
    const int kt = (s & 7) * 32;
    const unsigned short* __restrict__ W = (s >> 3) ? Wr2 : Wl2;
    bf16x8 bh[4], bl[4];
#pragma unroll
    for (int nf = 0; nf < 4; ++nf) {
      const int off = (wc * 64 + nf * 16 + l15) * H + kt + lk * 8;
      bh[nf] = *reinterpret_cast<const bf16x8*>(W + off);
      bl[nf] = *reinterpret_cast<const bf16x8*>(W + 65536 + off);
    }
    bf16x8 ah[4], al[4];
#pragma unroll
    for (int mf = 0; mf < 4; ++mf) {
      const int o = (mf * 64 + lane) * 8;
      ah[mf] = *reinterpret_cast<const bf16x8*>(&lds[buf][0][o]);
      al[mf] = *reinterpret_cast<const bf16x8*>(&lds[buf][1][o]);
    }
#pragma unroll
    for (int mf = 0; mf < 4; ++mf)
#pragma unroll
      for (int nf = 0; nf < 4; ++nf) {
        acc[mf][nf] = __builtin_amdgcn_mfma_f32_16x16x32_bf16(ah[mf], bh[nf], acc[mf][nf], 0, 0, 0);
        acc[mf][nf] = __builtin_amdgcn_mfma_f32_16x16x32_bf16(ah[mf], bl[nf], acc[mf][nf], 0, 0, 0);
        acc[mf][nf] = __builtin_amdgcn_mfma_f32_16x16x32_bf16(al[mf], bh[nf], acc[mf][nf], 0, 0, 0);
      }
    if (s < 15) sconv(buf ^ 1);
    __syncthreads();
  }

  // epilogue: +bias, relu, f32 coalesced stores (4B/lane, 16-lane 64B runs)
#pragma unroll
  for (int nf = 0; nf < 4; ++nf) {
    const int c = wc * 64 + nf * 16 + l15;
    const float bv = bias[c];
#pragma unroll
    for (int mf = 0; mf < 4; ++mf) {
      const int r0 = m0 + mf * 16 + lk * 4;
#pragma unroll
      for (int j = 0; j < 4; ++j) {
        const int r = r0 + j;
        if (r < n_tgt) {
          float v = acc[mf][nf][j] + bv;
          if (relu) v = fmaxf(v, 0.f);
          Out[(size_t)r * H + c] = v;
        }
      }
    }
  }
}

// ---------------------------------------------------------------------------
// exclusive prefix sum of counts (B=4096) -> off[0..B], single block
// ---------------------------------------------------------------------------
__global__ __launch_bounds__(1024) void scan_kernel(
    const int* __restrict__ cnt, int* __restrict__ off, int B) {
  __shared__ int sdata[1024];
  const int t = threadIdx.x;
  const int base = t * 4;
  int c[4];
#pragma unroll
  for (int k = 0; k < 4; ++k) c[k] = (base + k < B) ? cnt[base + k] : 0;
  int s0 = c[0];
  int s1 = s0 + c[1];
  int s2 = s1 + c[2];
  int s3 = s2 + c[3];
  sdata[t] = s3;
  __syncthreads();
  for (int o = 1; o < 1024; o <<= 1) {
    int v = (t >= o) ? sdata[t - o] : 0;
    __syncthreads();
    sdata[t] += v;
    __syncthreads();
  }
  int excl = sdata[t] - s3;
  if (base + 0 < B) off[base + 0] = excl;
  if (base + 1 < B) off[base + 1] = excl + s0;
  if (base + 2 < B) off[base + 2] = excl + s1;
  if (base + 3 < B) off[base + 3] = excl + s2;
  if (t == 1023) off[B] = sdata[1023];
}

// ---------------------------------------------------------------------------
// pooled[b] = mean over users of user_out[idx[off[b]..off[b]+cnt[b])]
// 256-thread blocks, 4 segments per block.
// ---------------------------------------------------------------------------
__global__ __launch_bounds__(256) void pool_kernel(
    const float* __restrict__ uo, const int* __restrict__ idx,
    const int* __restrict__ off, const int* __restrict__ cnt,
    float* __restrict__ pooled) {
  const int b = blockIdx.x * 4 + (threadIdx.x >> 6);
  const int lane = threadIdx.x & 63;
  const int o = off[b];
  const int n = cnt[b];
  float4 acc = {0.f, 0.f, 0.f, 0.f};
  for (int k = 0; k < n; ++k) {
    int u = idx[o + k];
    const float4 v =
        *reinterpret_cast<const float4*>(uo + (size_t)u * H + lane * 4);
    acc.x += v.x; acc.y += v.y; acc.z += v.z; acc.w += v.w;
  }
  const float inv = 1.0f / (float)n;
  acc.x *= inv; acc.y *= inv; acc.z *= inv; acc.w *= inv;
  *reinterpret_cast<float4*>(pooled + (size_t)b * H + lane * 4) = acc;
}

// ---------------------------------------------------------------------------
// out[b] = [res_out[b], pooled[b]] @ W_out^T + b_out   (W_out: (2,512))
// ---------------------------------------------------------------------------
__global__ __launch_bounds__(256) void out_kernel(
    const float* __restrict__ res_out, const float* __restrict__ pooled,
    const float* __restrict__ Wout, const float* __restrict__ bout,
    float* __restrict__ out) {
  const int b = blockIdx.x;
  const int t = threadIdx.x;  // 0..255
  const float e0 = res_out[(size_t)b * H + t];
  const float e1 = pooled[(size_t)b * H + t];
  float p0 = e0 * Wout[t] + e1 * Wout[256 + t];
  float p1 = e0 * Wout[512 + t] + e1 * Wout[768 + t];
#pragma unroll
  for (int o = 32; o >= 1; o >>= 1) {
    p0 += __shfl_down(p0, o, 64);
    p1 += __shfl_down(p1, o, 64);
  }
  __shared__ float s0[4], s1[4];
  const int w = t >> 6, lane = t & 63;
  if (lane == 0) { s0[w] = p0; s1[w] = p1; }
  __syncthreads();
  if (t == 0) out[(size_t)b * 2 + 0] = s0[0] + s0[1] + s0[2] + s0[3] + bout[0];
  if (t == 1) out[(size_t)b * 2 + 1] = s1[0] + s1[1] + s1[2] + s1[3] + bout[1];
}

// ---------------------------------------------------------------------------
extern "C" void kernel_launch(void* const* d_in, const int* in_sizes, int n_in,
                              void* d_out, int out_size, void* d_ws,
                              size_t ws_size, hipStream_t stream) {
  const float* res_x  = (const float*)d_in[0];
  const float* user_x = (const float*)d_in[1];
  const int* res_ei[3]  = {(const int*)d_in[2], (const int*)d_in[3], (const int*)d_in[4]};
  const int* user_ei[3] = {(const int*)d_in[5], (const int*)d_in[6], (const int*)d_in[7]};

  const int* counts;
  const int* inv_idx;
  if (in_sizes[8] == 4096) { counts = (const int*)d_in[8]; inv_idx = (const int*)d_in[9]; }
  else                     { counts = (const int*)d_in[9]; inv_idx = (const int*)d_in[8]; }

  const float* rW[9]; const float* uW[9];
  for (int i = 0; i < 9; ++i) rW[i] = (const float*)d_in[10 + i];
  for (int i = 0; i < 9; ++i) uW[i] = (const float*)d_in[19 + i];
  const float* Wout = (const float*)d_in[28];
  const float* bout = (const float*)d_in[29];

  // workspace layout (floats; all features f32)
  float* ws = (float*)d_ws;
  float* AGG  = ws;                        // 60000*256
  float* B1   = AGG  + (size_t)60000 * H;  // 60000*256
  float* B2   = B1   + (size_t)60000 * H;  // 20000*256
  float* U3   = B2   + (size_t)20000 * H;  // 8192*256
  float* R3   = U3   + (size_t)8192  * H;  // 4096*256
  float* POOL = R3   + (size_t)4096  * H;  // 4096*256
  unsigned short* WB = (unsigned short*)(POOL + (size_t)4096 * H);  // 12*131072 us
  int* OFF = (int*)(WB + (size_t)12 * 131072);

  // weight prep order: uWl0,uWr0,uWl1,uWr1,uWl2,uWr2, rWl0,rWr0,...
  PtrPack pk;
  pk.p[0] = uW[0]; pk.p[1] = uW[2];
  pk.p[2] = uW[3]; pk.p[3] = uW[5];
  pk.p[4] = uW[6]; pk.p[5] = uW[8];
  pk.p[6] = rW[0]; pk.p[7] = rW[2];
  pk.p[8] = rW[3]; pk.p[9] = rW[5];
  pk.p[10] = rW[6]; pk.p[11] = rW[8];
  wprep_kernel<<<3072, 256, 0, stream>>>(pk, WB);

  auto Wm = [&](int m) { return WB + (size_t)m * 131072; };
  auto gemm_grid = [](int n) { return (n + 63) / 64; };
  auto agg_grid = [](int n) { return (n + 3) / 4; };

  // ---- user branch: 250000 -> 60000 -> 20000 -> 8192
  agg_kernel<<<agg_grid(60000), 256, 0, stream>>>(user_x, user_ei[0], AGG, 60000);
  sage_gemm_mfma<<<gemm_grid(60000), 256, 0, stream>>>(
      AGG, user_x, Wm(0), Wm(1), uW[1], B1, 60000, 1);
  agg_kernel<<<agg_grid(20000), 256, 0, stream>>>(B1, user_ei[1], AGG, 20000);
  sage_gemm_mfma<<<gemm_grid(20000), 256, 0, stream>>>(
      AGG, B1, Wm(2), Wm(3), uW[4], B2, 20000, 0);
  agg_kernel<<<agg_grid(8192), 256, 0, stream>>>(B2, user_ei[2], AGG, 8192);
  sage_gemm_mfma<<<gemm_grid(8192), 256, 0, stream>>>(
      AGG, B2, Wm(4), Wm(5), uW[7], U3, 8192, 1);

  // ---- res branch: 200000 -> 50000 -> 12000 -> 4096
  agg_kernel<<<agg_grid(50000), 256, 0, stream>>>(res_x, res_ei[0], AGG, 50000);
  sage_gemm_mfma<<<gemm_grid(50000), 256, 0, stream>>>(
      AGG, res_x, Wm(6), Wm(7), rW[1], B1, 50000, 1);
  agg_kernel<<<agg_grid(12000), 256, 0, stream>>>(B1, res_ei[1], AGG, 12000);
  sage_gemm_mfma<<<gemm_grid(12000), 256, 0, stream>>>(
      AGG, B1, Wm(8), Wm(9), rW[4], B2, 12000, 0);
  agg_kernel<<<agg_grid(4096), 256, 0, stream>>>(B2, res_ei[2], AGG, 4096);
  sage_gemm_mfma<<<gemm_grid(4096), 256, 0, stream>>>(
      AGG, B2, Wm(10), Wm(11), rW[7], R3, 4096, 1);

  // ---- pooling + final linear
  scan_kernel<<<1, 1024, 0, stream>>>(counts, OFF, 4096);
  pool_kernel<<<1024, 256, 0, stream>>>(U3, inv_idx, OFF, counts, POOL);
  out_kernel<<<4096, 256, 0, stream>>>(R3, POOL, Wout, bout, (float*)d_out);
}

// Round 7
// 942.020 us; speedup vs baseline: 1.3444x; 1.1333x over previous
//
#include <hip/hip_runtime.h>

#define H 256
#define FANOUT 10

typedef __attribute__((ext_vector_type(8))) short bf16x8;
typedef __attribute__((ext_vector_type(4))) float f32x4;

__device__ __forceinline__ unsigned short f2bf(float x) {
  unsigned int u = __float_as_uint(x);
  u += 0x7FFFu + ((u >> 16) & 1u);
  return (unsigned short)(u >> 16);
}
__device__ __forceinline__ float bf2f(unsigned short h) {
  return __uint_as_float(((unsigned int)h) << 16);
}

// ---------------------------------------------------------------------------
// Weight prep: 12 (256,256) f32 matrices -> bf16 hi plane + lo plane each.
// WB layout: [mat][hi 65536 | lo 65536] ushorts.
// mats: 0:uWl0 1:uWr0 2:uWl1 3:uWr1 4:uWl2 5:uWr2 6:rWl0 ... 11:rWr2
// ---------------------------------------------------------------------------
struct PtrPack { const float* p[12]; };

__global__ __launch_bounds__(256) void wprep_kernel(PtrPack pk,
                                                    unsigned short* __restrict__ WB) {
  int g = blockIdx.x * 256 + threadIdx.x;  // 12*65536 total
  int mat = g >> 16;
  int e = g & 65535;
  float x = pk.p[mat][e];
  unsigned short h = f2bf(x);
  float r = x - bf2f(h);
  WB[(size_t)mat * 131072 + e] = h;
  WB[(size_t)mat * 131072 + 65536 + e] = f2bf(r);
}

// ---------------------------------------------------------------------------
// Merged-branch agg: agg[t][:] = 0.1 * sum_{k<10} src[row[t*10+k]][:]
// Blocks [0,nU4) -> user targets, [nU4,..) -> res targets.
// 4 targets per 256-thread block (all n divisible by 4).
// ---------------------------------------------------------------------------
__global__ __launch_bounds__(256) void agg_pair(
    const float* __restrict__ srcU, const int* __restrict__ rowU,
    float* __restrict__ aggU, int nU4,
    const float* __restrict__ srcR, const int* __restrict__ rowR,
    float* __restrict__ aggR) {
  const int blk = blockIdx.x;
  const float* __restrict__ src;
  const int* __restrict__ row;
  float* __restrict__ agg;
  int t;
  if (blk < nU4) {
    src = srcU; row = rowU; agg = aggU;
    t = blk * 4 + (threadIdx.x >> 6);
  } else {
    src = srcR; row = rowR; agg = aggR;
    t = (blk - nU4) * 4 + (threadIdx.x >> 6);
  }
  const int lane = threadIdx.x & 63;
  const int base = t * FANOUT;
  float4 acc = {0.f, 0.f, 0.f, 0.f};
#pragma unroll
  for (int k = 0; k < FANOUT; ++k) {
    int r = row[base + k];
    const float4 v =
        *reinterpret_cast<const float4*>(src + (size_t)r * H + lane * 4);
    acc.x += v.x; acc.y += v.y; acc.z += v.z; acc.w += v.w;
  }
  acc.x *= 0.1f; acc.y *= 0.1f; acc.z *= 0.1f; acc.w *= 0.1f;
  *reinterpret_cast<float4*>(agg + (size_t)t * H + lane * 4) = acc;
}

// ---------------------------------------------------------------------------
// Merged-branch MFMA GEMM: Out = Af @ Wl^T + bias + Xf @ Wr^T (+relu).
// Split-bf16 (hi+lo): 3 MFMA per fragment pair. Tile 64x256, 4 waves.
// A staged f32->bf16 hi/lo into LDS, fragment-native layout (conflict-free).
// B (weights) prefetched one K-step ahead into a ping-pong register set,
// so each step's MFMA cluster depends only on lgkmcnt (LDS), not L2 latency.
// ---------------------------------------------------------------------------
__global__ __launch_bounds__(256, 2) void sage_gemm_mfma(
    const float* __restrict__ AfU, const float* __restrict__ XfU,
    const unsigned short* __restrict__ WlU, const unsigned short* __restrict__ WrU,
    const float* __restrict__ bU, float* __restrict__ OutU, int nU,
    const float* __restrict__ AfR, const float* __restrict__ XfR,
    const unsigned short* __restrict__ WlR, const unsigned short* __restrict__ WrR,
    const float* __restrict__ bR, float* __restrict__ OutR, int nR,
    int relu) {
  __shared__ unsigned short lds[2][2][4 * 64 * 8];  // 16 KB
  const int nbU = (nU + 63) >> 6;
  const bool isU = (int)blockIdx.x < nbU;
  const float* __restrict__ Af = isU ? AfU : AfR;
  const float* __restrict__ Xf = isU ? XfU : XfR;
  const unsigned short* __restrict__ Wl2 = isU ? WlU : WlR;
  const unsigned short* __restrict__ Wr2 = isU ? WrU : WrR;
  const float* __restrict__ bias = isU ? bU : bR;
  float* __restrict__ Out = isU ? OutU : OutR;
  const int n_tgt = isU ? nU : nR;
  const int m0 = (isU ? (int)blockIdx.x : (int)blockIdx.x - nbU) * 64;

  const int tid = threadIdx.x;
  const int lane = tid & 63, wc = tid >> 6;
  const int l15 = lane & 15, lk = lane >> 4;
  const int srow = tid >> 2, sch = tid & 3;  // staging: row 0..63, k-chunk 0..3
  const int grow = m0 + srow;
  const bool sok = grow < n_tgt;
  // fragment-native LDS slot (16B per thread; linear per wave, 0 conflicts)
  const int ldsoff = (((srow >> 4) * 64) + (srow & 15) + sch * 16) * 8;

  f32x4 acc[4][4];
#pragma unroll
  for (int i = 0; i < 4; ++i)
#pragma unroll
    for (int j = 0; j < 4; ++j) acc[i][j] = (f32x4){0.f, 0.f, 0.f, 0.f};

  float4 f0 = {0, 0, 0, 0}, f1 = {0, 0, 0, 0};
  auto gload = [&](int s) {
    if (sok) {
      const float* S = (s >> 3) ? Xf : Af;
      const float* p = S + (size_t)grow * H + (s & 7) * 32 + sch * 8;
      f0 = *reinterpret_cast<const float4*>(p);
      f1 = *reinterpret_cast<const float4*>(p + 4);
    } else {
      f0 = (float4){0, 0, 0, 0};
      f1 = (float4){0, 0, 0, 0};
    }
  };
  auto sconv = [&](int buf) {
    const float xs[8] = {f0.x, f0.y, f0.z, f0.w, f1.x, f1.y, f1.z, f1.w};
    bf16x8 vh, vl;
#pragma unroll
    for (int i = 0; i < 8; ++i) {
      unsigned short h = f2bf(xs[i]);
      vh[i] = (short)h;
      vl[i] = (short)f2bf(xs[i] - bf2f(h));
    }
    *reinterpret_cast<bf16x8*>(&lds[buf][0][ldsoff]) = vh;
    *reinterpret_cast<bf16x8*>(&lds[buf][1][ldsoff]) = vl;
  };
  auto loadB = [&](int s, bf16x8* bh, bf16x8* bl) {
    const unsigned short* __restrict__ W = (s >> 3) ? Wr2 : Wl2;
    const int kt = (s & 7) * 32;
#pragma unroll
    for (int nf = 0; nf < 4; ++nf) {
      const int off = (wc * 64 + nf * 16 + l15) * H + kt + lk * 8;
      bh[nf] = *reinterpret_cast<const bf16x8*>(W + off);
      bl[nf] = *reinterpret_cast<const bf16x8*>(W + 65536 + off);
    }
  };
  auto dsreadA = [&](int buf, bf16x8* ah, bf16x8* al) {
#pragma unroll
    for (int mf = 0; mf < 4; ++mf) {
      const int o = (mf * 64 + lane) * 8;
      ah[mf] = *reinterpret_cast<const bf16x8*>(&lds[buf][0][o]);
      al[mf] = *reinterpret_cast<const bf16x8*>(&lds[buf][1][o]);
    }
  };
  auto mfma16 = [&](bf16x8* ah, bf16x8* al, bf16x8* bh, bf16x8* bl) {
#pragma unroll
    for (int mf = 0; mf < 4; ++mf)
#pragma unroll
      for (int nf = 0; nf < 4; ++nf) {
        acc[mf][nf] = __builtin_amdgcn_mfma_f32_16x16x32_bf16(ah[mf], bh[nf], acc[mf][nf], 0, 0, 0);
        acc[mf][nf] = __builtin_amdgcn_mfma_f32_16x16x32_bf16(ah[mf], bl[nf], acc[mf][nf], 0, 0, 0);
        acc[mf][nf] = __builtin_amdgcn_mfma_f32_16x16x32_bf16(al[mf], bh[nf], acc[mf][nf], 0, 0, 0);
      }
  };

  bf16x8 bh0[4], bl0[4], bh1[4], bl1[4];
  bf16x8 ah[4], al[4];

  // prologue: stage A(0), prefetch B(0)
  gload(0);
  sconv(0);
  loadB(0, bh0, bl0);
  __syncthreads();

  for (int ss = 0; ss < 8; ++ss) {
    // even step s = 2*ss (A buf 0, B set 0); prefetch s+1 into set 1
    {
      const int s = 2 * ss;
      gload(s + 1);
      loadB(s + 1, bh1, bl1);
      dsreadA(0, ah, al);
      mfma16(ah, al, bh0, bl0);
      sconv(1);
      __syncthreads();
    }
    // odd step s = 2*ss+1 (A buf 1, B set 1); prefetch s+1 into set 0
    {
      const int s = 2 * ss + 1;
      if (s < 15) {
        gload(s + 1);
        loadB(s + 1, bh0, bl0);
      }
      dsreadA(1, ah, al);
      mfma16(ah, al, bh1, bl1);
      if (s < 15) {
        sconv(0);
        __syncthreads();
      }
    }
  }

  // epilogue: +bias, relu, coalesced f32 stores
#pragma unroll
  for (int nf = 0; nf < 4; ++nf) {
    const int c = wc * 64 + nf * 16 + l15;
    const float bv = bias[c];
#pragma unroll
    for (int mf = 0; mf < 4; ++mf) {
      const int r0 = m0 + mf * 16 + lk * 4;
#pragma unroll
      for (int j = 0; j < 4; ++j) {
        const int r = r0 + j;
        if (r < n_tgt) {
          float v = acc[mf][nf][j] + bv;
          if (relu) v = fmaxf(v, 0.f);
          Out[(size_t)r * H + c] = v;
        }
      }
    }
  }
}

// ---------------------------------------------------------------------------
// exclusive prefix sum of counts (B=4096) -> off[0..B], single block
// ---------------------------------------------------------------------------
__global__ __launch_bounds__(1024) void scan_kernel(
    const int* __restrict__ cnt, int* __restrict__ off, int B) {
  __shared__ int sdata[1024];
  const int t = threadIdx.x;
  const int base = t * 4;
  int c[4];
#pragma unroll
  for (int k = 0; k < 4; ++k) c[k] = (base + k < B) ? cnt[base + k] : 0;
  int s0 = c[0];
  int s1 = s0 + c[1];
  int s2 = s1 + c[2];
  int s3 = s2 + c[3];
  sdata[t] = s3;
  __syncthreads();
  for (int o = 1; o < 1024; o <<= 1) {
    int v = (t >= o) ? sdata[t - o] : 0;
    __syncthreads();
    sdata[t] += v;
    __syncthreads();
  }
  int excl = sdata[t] - s3;
  if (base + 0 < B) off[base + 0] = excl;
  if (base + 1 < B) off[base + 1] = excl + s0;
  if (base + 2 < B) off[base + 2] = excl + s1;
  if (base + 3 < B) off[base + 3] = excl + s2;
  if (t == 1023) off[B] = sdata[1023];
}

// ---------------------------------------------------------------------------
// Fused pool + output head. One block per b:
//   pooled = mean over users of U3[idx[off[b]..off[b]+cnt[b])]  (4-wave split)
//   out[b] = [res_out[b], pooled] @ W_out^T + b_out
// ---------------------------------------------------------------------------
__global__ __launch_bounds__(256) void poolout_kernel(
    const float* __restrict__ uo, const int* __restrict__ idx,
    const int* __restrict__ off, const int* __restrict__ cnt,
    const float* __restrict__ res_out,
    const float* __restrict__ Wout, const float* __restrict__ bout,
    float* __restrict__ out) {
  const int b = blockIdx.x;
  const int t = threadIdx.x;
  const int w = t >> 6, lane = t & 63;
  const int o = off[b], n = cnt[b];
  float4 acc = {0.f, 0.f, 0.f, 0.f};
  for (int k = w; k < n; k += 4) {
    int u = idx[o + k];
    const float4 v =
        *reinterpret_cast<const float4*>(uo + (size_t)u * H + lane * 4);
    acc.x += v.x; acc.y += v.y; acc.z += v.z; acc.w += v.w;
  }
  __shared__ float pl[4][256];
  *reinterpret_cast<float4*>(&pl[w][lane * 4]) = acc;
  __syncthreads();
  const float inv = 1.0f / (float)n;
  const float e1 = (pl[0][t] + pl[1][t] + pl[2][t] + pl[3][t]) * inv;
  const float e0 = res_out[(size_t)b * H + t];
  float p0 = e0 * Wout[t] + e1 * Wout[256 + t];
  float p1 = e0 * Wout[512 + t] + e1 * Wout[768 + t];
#pragma unroll
  for (int od = 32; od >= 1; od >>= 1) {
    p0 += __shfl_down(p0, od, 64);
    p1 += __shfl_down(p1, od, 64);
  }
  __shared__ float s0[4], s1[4];
  if (lane == 0) { s0[w] = p0; s1[w] = p1; }
  __syncthreads();
  if (t == 0) out[(size_t)b * 2 + 0] = s0[0] + s0[1] + s0[2] + s0[3] + bout[0];
  if (t == 1) out[(size_t)b * 2 + 1] = s1[0] + s1[1] + s1[2] + s1[3] + bout[1];
}

// ---------------------------------------------------------------------------
extern "C" void kernel_launch(void* const* d_in, const int* in_sizes, int n_in,
                              void* d_out, int out_size, void* d_ws,
                              size_t ws_size, hipStream_t stream) {
  const float* res_x  = (const float*)d_in[0];
  const float* user_x = (const float*)d_in[1];
  const int* res_ei[3]  = {(const int*)d_in[2], (const int*)d_in[3], (const int*)d_in[4]};
  const int* user_ei[3] = {(const int*)d_in[5], (const int*)d_in[6], (const int*)d_in[7]};

  const int* counts;
  const int* inv_idx;
  if (in_sizes[8] == 4096) { counts = (const int*)d_in[8]; inv_idx = (const int*)d_in[9]; }
  else                     { counts = (const int*)d_in[9]; inv_idx = (const int*)d_in[8]; }

  const float* rW[9]; const float* uW[9];
  for (int i = 0; i < 9; ++i) rW[i] = (const float*)d_in[10 + i];
  for (int i = 0; i < 9; ++i) uW[i] = (const float*)d_in[19 + i];
  const float* Wout = (const float*)d_in[28];
  const float* bout = (const float*)d_in[29];

  // workspace layout (floats; all features f32, no aliasing)
  float* ws = (float*)d_ws;
  float* AGGU = ws;                          // 60000*256
  float* AGGR = AGGU + (size_t)60000 * H;    // 50000*256
  float* UB1  = AGGR + (size_t)50000 * H;    // 60000*256
  float* RB1  = UB1  + (size_t)60000 * H;    // 50000*256
  float* UB2  = RB1  + (size_t)50000 * H;    // 20000*256
  float* RB2  = UB2  + (size_t)20000 * H;    // 12000*256
  float* U3   = RB2  + (size_t)12000 * H;    // 8192*256
  float* R3   = U3   + (size_t)8192  * H;    // 4096*256
  unsigned short* WB = (unsigned short*)(R3 + (size_t)4096 * H);  // 12*131072
  int* OFF = (int*)(WB + (size_t)12 * 131072);

  PtrPack pk;
  pk.p[0] = uW[0]; pk.p[1] = uW[2];
  pk.p[2] = uW[3]; pk.p[3] = uW[5];
  pk.p[4] = uW[6]; pk.p[5] = uW[8];
  pk.p[6] = rW[0]; pk.p[7] = rW[2];
  pk.p[8] = rW[3]; pk.p[9] = rW[5];
  pk.p[10] = rW[6]; pk.p[11] = rW[8];
  wprep_kernel<<<3072, 256, 0, stream>>>(pk, WB);

  auto Wm = [&](int m) { return WB + (size_t)m * 131072; };
  auto gb = [](int n) { return (n + 63) / 64; };

  // depth 0: user 250000->60000, res 200000->50000
  agg_pair<<<15000 + 12500, 256, 0, stream>>>(user_x, user_ei[0], AGGU, 15000,
                                              res_x, res_ei[0], AGGR);
  sage_gemm_mfma<<<gb(60000) + gb(50000), 256, 0, stream>>>(
      AGGU, user_x, Wm(0), Wm(1), uW[1], UB1, 60000,
      AGGR, res_x,  Wm(6), Wm(7), rW[1], RB1, 50000, 1);

  // depth 1: user 60000->20000, res 50000->12000
  agg_pair<<<5000 + 3000, 256, 0, stream>>>(UB1, user_ei[1], AGGU, 5000,
                                            RB1, res_ei[1], AGGR);
  sage_gemm_mfma<<<gb(20000) + gb(12000), 256, 0, stream>>>(
      AGGU, UB1, Wm(2), Wm(3), uW[4], UB2, 20000,
      AGGR, RB1, Wm(8), Wm(9), rW[4], RB2, 12000, 0);

  // depth 2: user 20000->8192, res 12000->4096
  agg_pair<<<2048 + 1024, 256, 0, stream>>>(UB2, user_ei[2], AGGU, 2048,
                                            RB2, res_ei[2], AGGR);
  sage_gemm_mfma<<<gb(8192) + gb(4096), 256, 0, stream>>>(
      AGGU, UB2, Wm(4), Wm(5),  uW[7], U3, 8192,
      AGGR, RB2, Wm(10), Wm(11), rW[7], R3, 4096, 1);

  // pooling + output head
  scan_kernel<<<1, 1024, 0, stream>>>(counts, OFF, 4096);
  poolout_kernel<<<4096, 256, 0, stream>>>(U3, inv_idx, OFF, counts, R3,
                                           Wout, bout, (float*)d_out);
}